// Round 3
// baseline (930.610 us; speedup 1.0000x reference)
//
#include <hip/hip_runtime.h>
#include <math.h>

#define NROWS 524288
#define DIN 64
#define HD 128
#define DZ 16
#define KC 256
#define BETA 0.25f

#define TILE_R 64
#define NTHR 512
#define NWAVE 8

// ---- LDS layout (floats) ----
// region1: sH 64x132. Lifetime: feats tile (cols 0..63) -> h1 -> h2 (in-place) ->
//          dead after phase C -> bestd/besti overlay.
//          b128 reads: start bank quad = (132r+4q)%32 = 4(r+q)%32 -> 8 lanes/quad = balanced.
// region0: cnorm (256) + Zs (64x20). Never overlapped.
#define SH_PITCH 132
#define ZPITCH 20
#define REG1_SZ (TILE_R * SH_PITCH)          // 8448 floats
#define R0_ZS 256
#define REG0_SZ (R0_ZS + TILE_R * ZPITCH)    // 1536 floats
#define SMEM_FLOATS (REG1_SZ + REG0_SZ)      // 9984 floats = 39936 B -> 4 blocks/CU
// overlays inside region1 (valid after barrier5: all sH reads complete)
#define OV_BESTD 0
#define OV_BESTI NTHR                         // 512

__global__ __launch_bounds__(NTHR, 8)
void encoder_main(const float* __restrict__ feats,
                  const float* __restrict__ W1, const float* __restrict__ b1,
                  const float* __restrict__ W2, const float* __restrict__ b2,
                  const float* __restrict__ Wmu, const float* __restrict__ bmu,
                  const float* __restrict__ Wlv, const float* __restrict__ blv,
                  const float* __restrict__ codebook,
                  const float* __restrict__ eps,
                  float* __restrict__ out, float* __restrict__ loss_ws)
{
  __shared__ float smem[SMEM_FLOATS];
  float* sH     = smem;                      // region1
  float* cnormS = smem + REG1_SZ;            // region0
  float* Zs     = smem + REG1_SZ + R0_ZS;
  float* bestdS = sH + OV_BESTD;             // overlay (after barrier5)
  int*   bestiS = (int*)(sH + OV_BESTI);

  const int t = threadIdx.x;
  const int r = t & 63;                                   // row in tile == lane id
  const int wv = __builtin_amdgcn_readfirstlane(t >> 6);  // wave id 0..7, uniform
  const int row0 = blockIdx.x * TILE_R;

  // ---- stage feats tile into sH cols 0..63 (coalesced float4; 2 per thread) ----
  {
    const float4* __restrict__ src = (const float4*)(feats + (size_t)row0 * DIN);
    #pragma unroll
    for (int i = 0; i < 2; ++i) {
      int v = t + i * NTHR;             // float4 index 0..1023
      float4 f4 = src[v];
      int rr = v >> 4;                  // 16 float4 per row
      int cc = (v & 15) * 4;
      *(float4*)(sH + rr * SH_PITCH + cc) = f4;
    }
  }
  __syncthreads();   // b0: feats staged

  // ---- phase A: h1 = relu(feats @ W1 + b1); thread = (row r, 16 cols @ wv*16) ----
  float accA[16];
  {
    const int j0 = wv * 16;
    const float* __restrict__ bb = b1 + j0;               // uniform -> scalar
    #pragma unroll
    for (int i = 0; i < 16; ++i) accA[i] = bb[i];
    const float4* __restrict__ fr = (const float4*)(sH + r * SH_PITCH);
    #pragma unroll 4
    for (int k4 = 0; k4 < DIN / 4; ++k4) {
      float4 f = fr[k4];                                  // ds_read_b128, balanced
      const float* __restrict__ w0 = W1 + (k4 * 4 + 0) * HD + j0;  // uniform -> s_load
      const float* __restrict__ w1 = W1 + (k4 * 4 + 1) * HD + j0;
      const float* __restrict__ w2 = W1 + (k4 * 4 + 2) * HD + j0;
      const float* __restrict__ w3 = W1 + (k4 * 4 + 3) * HD + j0;
      #pragma unroll
      for (int i = 0; i < 16; ++i) accA[i] = fmaf(f.x, w0[i], accA[i]);
      #pragma unroll
      for (int i = 0; i < 16; ++i) accA[i] = fmaf(f.y, w1[i], accA[i]);
      #pragma unroll
      for (int i = 0; i < 16; ++i) accA[i] = fmaf(f.z, w2[i], accA[i]);
      #pragma unroll
      for (int i = 0; i < 16; ++i) accA[i] = fmaf(f.w, w3[i], accA[i]);
    }
  }

  // ---- codebook norms (one code per thread, t<256; region0, no hazard) ----
  if (t < KC) {
    const float4* __restrict__ crow = (const float4*)(codebook + t * DZ);
    float4 a = crow[0], b = crow[1], c = crow[2], d = crow[3];
    cnormS[t] = a.x*a.x + a.y*a.y + a.z*a.z + a.w*a.w
              + b.x*b.x + b.y*b.y + b.z*b.z + b.w*b.w
              + c.x*c.x + c.y*c.y + c.z*c.z + c.w*c.w
              + d.x*d.x + d.y*d.y + d.z*d.z + d.w*d.w;
  }
  __syncthreads();   // b1: all feats reads complete -> sH writable

  {
    const int j0 = wv * 16;
    float* hrow = sH + r * SH_PITCH + j0;
    #pragma unroll
    for (int q = 0; q < 4; ++q)
      *(float4*)(hrow + 4 * q) = make_float4(fmaxf(accA[4*q+0], 0.0f), fmaxf(accA[4*q+1], 0.0f),
                                             fmaxf(accA[4*q+2], 0.0f), fmaxf(accA[4*q+3], 0.0f));
  }
  __syncthreads();   // b2: h1 visible

  // ---- phase B: h2 = relu(h1 @ W2 + b2), in-place over sH ----
  {
    const int j0 = wv * 16;
    float acc[16];
    const float* __restrict__ bb = b2 + j0;
    #pragma unroll
    for (int i = 0; i < 16; ++i) acc[i] = bb[i];
    const float4* __restrict__ hr = (const float4*)(sH + r * SH_PITCH);
    #pragma unroll 4
    for (int k4 = 0; k4 < HD / 4; ++k4) {
      float4 f = hr[k4];
      const float* __restrict__ w0 = W2 + (k4 * 4 + 0) * HD + j0;
      const float* __restrict__ w1 = W2 + (k4 * 4 + 1) * HD + j0;
      const float* __restrict__ w2 = W2 + (k4 * 4 + 2) * HD + j0;
      const float* __restrict__ w3 = W2 + (k4 * 4 + 3) * HD + j0;
      #pragma unroll
      for (int i = 0; i < 16; ++i) acc[i] = fmaf(f.x, w0[i], acc[i]);
      #pragma unroll
      for (int i = 0; i < 16; ++i) acc[i] = fmaf(f.y, w1[i], acc[i]);
      #pragma unroll
      for (int i = 0; i < 16; ++i) acc[i] = fmaf(f.z, w2[i], acc[i]);
      #pragma unroll
      for (int i = 0; i < 16; ++i) acc[i] = fmaf(f.w, w3[i], acc[i]);
    }
    __syncthreads();  // b3: ALL h1 reads complete before overwrite
    float* hrow = sH + r * SH_PITCH + j0;
    #pragma unroll
    for (int q = 0; q < 4; ++q)
      *(float4*)(hrow + 4 * q) = make_float4(fmaxf(acc[4*q+0], 0.0f), fmaxf(acc[4*q+1], 0.0f),
                                             fmaxf(acc[4*q+2], 0.0f), fmaxf(acc[4*q+3], 0.0f));
  }
  __syncthreads();   // b4: h2 visible

  // ---- phase C: every wave computes mu AND lv for 2 cols (c0 = wv*2). ----
  // Same per-(r,c) fma chains as before -> bit-identical mu/lv/z. No cross-wave exchange.
  {
    const int c0 = wv * 2;
    const size_t zb = (size_t)(row0 + r) * DZ + c0;
    float2 ev = *(const float2*)(eps + zb);               // issue early, consumed post-loop
    float accM[2], accL[2];
    accM[0] = bmu[c0]; accM[1] = bmu[c0 + 1];
    accL[0] = blv[c0]; accL[1] = blv[c0 + 1];
    const float4* __restrict__ hr = (const float4*)(sH + r * SH_PITCH);
    #pragma unroll 4
    for (int k4 = 0; k4 < HD / 4; ++k4) {
      float4 h4 = hr[k4];
      const float* __restrict__ wm0 = Wmu + (k4 * 4 + 0) * DZ + c0;  // uniform -> s_load
      const float* __restrict__ wm1 = Wmu + (k4 * 4 + 1) * DZ + c0;
      const float* __restrict__ wm2 = Wmu + (k4 * 4 + 2) * DZ + c0;
      const float* __restrict__ wm3 = Wmu + (k4 * 4 + 3) * DZ + c0;
      const float* __restrict__ wl0 = Wlv + (k4 * 4 + 0) * DZ + c0;
      const float* __restrict__ wl1 = Wlv + (k4 * 4 + 1) * DZ + c0;
      const float* __restrict__ wl2 = Wlv + (k4 * 4 + 2) * DZ + c0;
      const float* __restrict__ wl3 = Wlv + (k4 * 4 + 3) * DZ + c0;
      #pragma unroll
      for (int i = 0; i < 2; ++i) {
        accM[i] = fmaf(h4.x, wm0[i], accM[i]);
        accM[i] = fmaf(h4.y, wm1[i], accM[i]);
        accM[i] = fmaf(h4.z, wm2[i], accM[i]);
        accM[i] = fmaf(h4.w, wm3[i], accM[i]);
        accL[i] = fmaf(h4.x, wl0[i], accL[i]);
        accL[i] = fmaf(h4.y, wl1[i], accL[i]);
        accL[i] = fmaf(h4.z, wl2[i], accL[i]);
        accL[i] = fmaf(h4.w, wl3[i], accL[i]);
      }
    }
    float zv0 = fmaf(ev.x, expf(0.5f * accL[0]), accM[0]);
    float zv1 = fmaf(ev.y, expf(0.5f * accL[1]), accM[1]);
    *(float2*)(Zs + r * ZPITCH + c0) = make_float2(zv0, zv1);   // region0, no hazard
    // stores now (registers die; drain cost at b5/b6 is small and hidden by occupancy)
    *(float2*)(out + zb)                          = make_float2(zv0, zv1);
    *(float2*)(out + (size_t)NROWS * DZ + zb)     = make_float2(accM[0], accM[1]);
    *(float2*)(out + (size_t)2 * NROWS * DZ + zb) = make_float2(accL[0], accL[1]);
  }
  __syncthreads();   // b5: Zs visible AND all sH reads done -> region1 overlay valid

  // ---- VQ: 8 threads/row, each scans 32 codes (ascending; strict < = argmin) ----
  float zreg[16];
  {
    const float4* __restrict__ zr = (const float4*)(Zs + r * ZPITCH);
    #pragma unroll
    for (int q = 0; q < 4; ++q) {
      float4 z4 = zr[q];
      zreg[4*q+0] = z4.x; zreg[4*q+1] = z4.y; zreg[4*q+2] = z4.z; zreg[4*q+3] = z4.w;
    }
  }
  {
    const int kk0 = wv * 32;
    float bd = 3.0e38f;
    int bi = kk0;
    #pragma unroll 8
    for (int c = 0; c < 32; ++c) {
      int kk = kk0 + c;
      const float* __restrict__ crow = codebook + kk * DZ;  // uniform -> s_load
      float dot = 0.0f;
      #pragma unroll
      for (int i = 0; i < 16; ++i) dot = fmaf(zreg[i], crow[i], dot);
      float s = fmaf(-2.0f, dot, cnormS[kk]);
      if (s < bd) { bd = s; bi = kk; }
    }
    bestdS[wv * 64 + r] = bd;
    bestiS[wv * 64 + r] = bi;
  }
  __syncthreads();   // b6: bestd/besti visible (last barrier)

  // ---- merge (wave 0): argmin across groups, gather z_q, loss partial, stores ----
  if (t < 64) {
    float bd = bestdS[r];
    int   bi = bestiS[r];
    #pragma unroll
    for (int g = 1; g < NWAVE; ++g) {   // ascending groups, strict <: lowest idx wins ties
      float d2 = bestdS[g * 64 + r];
      int   i2 = bestiS[g * 64 + r];
      if (d2 < bd) { bd = d2; bi = i2; }
    }
    const float4* __restrict__ cq = (const float4*)(codebook + bi * DZ);
    float4 q0 = cq[0], q1 = cq[1], q2 = cq[2], q3 = cq[3];
    const size_t base = (size_t)(row0 + r) * DZ;
    float4* __restrict__ gq = (float4*)(out + (size_t)3 * NROWS * DZ + base);
    gq[0] = q0; gq[1] = q1; gq[2] = q2; gq[3] = q3;

    float qq[16] = {q0.x,q0.y,q0.z,q0.w, q1.x,q1.y,q1.z,q1.w,
                    q2.x,q2.y,q2.z,q2.w, q3.x,q3.y,q3.z,q3.w};
    float lsum = 0.0f;
    #pragma unroll
    for (int i = 0; i < 16; ++i) {
      float d = qq[i] - zreg[i];        // zreg IS row r's z for wave 0 (bit-exact)
      lsum = fmaf(d, d, lsum);
    }
    #pragma unroll
    for (int off = 32; off > 0; off >>= 1) lsum += __shfl_down(lsum, off);
    if (t == 0) atomicAdd(loss_ws, lsum);
  }
}

__global__ void encoder_zero(float* ws) {
  if (threadIdx.x == 0 && blockIdx.x == 0) ws[0] = 0.0f;
}

__global__ void encoder_finalize(const float* __restrict__ ws, float* __restrict__ out) {
  if (threadIdx.x == 0 && blockIdx.x == 0) {
    // vq_loss = BETA * (commit + code) = 2*BETA*mean((zq-z)^2)
    out[(size_t)4 * NROWS * DZ] = ws[0] * (2.0f * BETA / (float)((size_t)NROWS * DZ));
  }
}

extern "C" void kernel_launch(void* const* d_in, const int* in_sizes, int n_in,
                              void* d_out, int out_size, void* d_ws, size_t ws_size,
                              hipStream_t stream) {
  (void)in_sizes; (void)n_in; (void)out_size; (void)ws_size;
  const float* feats    = (const float*)d_in[0];
  const float* W1       = (const float*)d_in[1];
  const float* b1       = (const float*)d_in[2];
  const float* W2       = (const float*)d_in[3];
  const float* b2       = (const float*)d_in[4];
  const float* Wmu      = (const float*)d_in[5];
  const float* bmu      = (const float*)d_in[6];
  const float* Wlv      = (const float*)d_in[7];
  const float* blv      = (const float*)d_in[8];
  const float* codebook = (const float*)d_in[9];
  const float* eps      = (const float*)d_in[10];
  float* out = (float*)d_out;
  float* ws  = (float*)d_ws;

  hipLaunchKernelGGL(encoder_zero, dim3(1), dim3(64), 0, stream, ws);
  hipLaunchKernelGGL(encoder_main, dim3(NROWS / TILE_R), dim3(NTHR), 0, stream,
                     feats, W1, b1, W2, b2, Wmu, bmu, Wlv, blv, codebook, eps, out, ws);
  hipLaunchKernelGGL(encoder_finalize, dim3(1), dim3(64), 0, stream, ws, out);
}

// Round 4
// 660.971 us; speedup vs baseline: 1.4079x; 1.4079x over previous
//
#include <hip/hip_runtime.h>
#include <math.h>

#define NROWS 524288
#define DIN 64
#define HD 128
#define DZ 16
#define KC 256
#define BETA 0.25f

#define TILE_R 64
#define NTHR 512
#define NWAVE 8

// ---- LDS layout (floats) ----
// region1: sH 64x132. Lifetime: feats tile (cols 0..63) -> h1 -> h2 (in-place) ->
//          dead after phase C -> bestd/besti overlay.
//          b128 reads: start bank quad = (132r+4q)%32 = 4(r+q)%32 -> 8 lanes/quad = balanced.
// region0: cnorm (256) + Zs (64x20). Never overlapped.
#define SH_PITCH 132
#define ZPITCH 20
#define REG1_SZ (TILE_R * SH_PITCH)          // 8448 floats
#define R0_ZS 256
#define REG0_SZ (R0_ZS + TILE_R * ZPITCH)    // 1536 floats
#define SMEM_FLOATS (REG1_SZ + REG0_SZ)      // 9984 floats = 39936 B -> 4 blocks/CU by LDS
// overlays inside region1 (valid after barrier5: all sH reads complete)
#define OV_BESTD 0
#define OV_BESTI NTHR                         // 512

// launch_bounds (512, 6): the proven round-2 bound. VGPR cap ~85 -> allocator lands ~40-48
// with zero spills (measured R2: VGPR 40, VALUBusy 67%). (512, 8) forced a 24-VGPR spilled
// allocation: dur 490 -> 770 us, VALUBusy 41%, FETCH +5 GB. Registers > occupancy here.
__global__ __launch_bounds__(NTHR, 6)
void encoder_main(const float* __restrict__ feats,
                  const float* __restrict__ W1, const float* __restrict__ b1,
                  const float* __restrict__ W2, const float* __restrict__ b2,
                  const float* __restrict__ Wmu, const float* __restrict__ bmu,
                  const float* __restrict__ Wlv, const float* __restrict__ blv,
                  const float* __restrict__ codebook,
                  const float* __restrict__ eps,
                  float* __restrict__ out, float* __restrict__ loss_ws)
{
  __shared__ float smem[SMEM_FLOATS];
  float* sH     = smem;                      // region1
  float* cnormS = smem + REG1_SZ;            // region0
  float* Zs     = smem + REG1_SZ + R0_ZS;
  float* bestdS = sH + OV_BESTD;             // overlay (after barrier5)
  int*   bestiS = (int*)(sH + OV_BESTI);

  const int t = threadIdx.x;
  const int r = t & 63;                                   // row in tile == lane id
  const int wv = __builtin_amdgcn_readfirstlane(t >> 6);  // wave id 0..7, uniform
  const int row0 = blockIdx.x * TILE_R;

  // ---- stage feats tile into sH cols 0..63 (coalesced float4; 2 per thread) ----
  {
    const float4* __restrict__ src = (const float4*)(feats + (size_t)row0 * DIN);
    #pragma unroll
    for (int i = 0; i < 2; ++i) {
      int v = t + i * NTHR;             // float4 index 0..1023
      float4 f4 = src[v];
      int rr = v >> 4;                  // 16 float4 per row
      int cc = (v & 15) * 4;
      *(float4*)(sH + rr * SH_PITCH + cc) = f4;
    }
  }
  __syncthreads();   // b0: feats staged

  // ---- phase A: h1 = relu(feats @ W1 + b1); thread = (row r, 16 cols @ wv*16) ----
  float accA[16];
  {
    const int j0 = wv * 16;
    const float* __restrict__ bb = b1 + j0;               // uniform -> scalar
    #pragma unroll
    for (int i = 0; i < 16; ++i) accA[i] = bb[i];
    const float4* __restrict__ fr = (const float4*)(sH + r * SH_PITCH);
    #pragma unroll 4
    for (int k4 = 0; k4 < DIN / 4; ++k4) {
      float4 f = fr[k4];                                  // ds_read_b128, balanced
      const float* __restrict__ w0 = W1 + (k4 * 4 + 0) * HD + j0;  // uniform -> s_load
      const float* __restrict__ w1 = W1 + (k4 * 4 + 1) * HD + j0;
      const float* __restrict__ w2 = W1 + (k4 * 4 + 2) * HD + j0;
      const float* __restrict__ w3 = W1 + (k4 * 4 + 3) * HD + j0;
      #pragma unroll
      for (int i = 0; i < 16; ++i) accA[i] = fmaf(f.x, w0[i], accA[i]);
      #pragma unroll
      for (int i = 0; i < 16; ++i) accA[i] = fmaf(f.y, w1[i], accA[i]);
      #pragma unroll
      for (int i = 0; i < 16; ++i) accA[i] = fmaf(f.z, w2[i], accA[i]);
      #pragma unroll
      for (int i = 0; i < 16; ++i) accA[i] = fmaf(f.w, w3[i], accA[i]);
    }
  }

  // ---- codebook norms (one code per thread, t<256; region0, no hazard) ----
  if (t < KC) {
    const float4* __restrict__ crow = (const float4*)(codebook + t * DZ);
    float4 a = crow[0], b = crow[1], c = crow[2], d = crow[3];
    cnormS[t] = a.x*a.x + a.y*a.y + a.z*a.z + a.w*a.w
              + b.x*b.x + b.y*b.y + b.z*b.z + b.w*b.w
              + c.x*c.x + c.y*c.y + c.z*c.z + c.w*c.w
              + d.x*d.x + d.y*d.y + d.z*d.z + d.w*d.w;
  }
  __syncthreads();   // b1: all feats reads complete -> sH writable

  {
    const int j0 = wv * 16;
    float* hrow = sH + r * SH_PITCH + j0;
    #pragma unroll
    for (int q = 0; q < 4; ++q)
      *(float4*)(hrow + 4 * q) = make_float4(fmaxf(accA[4*q+0], 0.0f), fmaxf(accA[4*q+1], 0.0f),
                                             fmaxf(accA[4*q+2], 0.0f), fmaxf(accA[4*q+3], 0.0f));
  }
  __syncthreads();   // b2: h1 visible

  // ---- phase B: h2 = relu(h1 @ W2 + b2), in-place over sH ----
  {
    const int j0 = wv * 16;
    float acc[16];
    const float* __restrict__ bb = b2 + j0;
    #pragma unroll
    for (int i = 0; i < 16; ++i) acc[i] = bb[i];
    const float4* __restrict__ hr = (const float4*)(sH + r * SH_PITCH);
    #pragma unroll 4
    for (int k4 = 0; k4 < HD / 4; ++k4) {
      float4 f = hr[k4];
      const float* __restrict__ w0 = W2 + (k4 * 4 + 0) * HD + j0;
      const float* __restrict__ w1 = W2 + (k4 * 4 + 1) * HD + j0;
      const float* __restrict__ w2 = W2 + (k4 * 4 + 2) * HD + j0;
      const float* __restrict__ w3 = W2 + (k4 * 4 + 3) * HD + j0;
      #pragma unroll
      for (int i = 0; i < 16; ++i) acc[i] = fmaf(f.x, w0[i], acc[i]);
      #pragma unroll
      for (int i = 0; i < 16; ++i) acc[i] = fmaf(f.y, w1[i], acc[i]);
      #pragma unroll
      for (int i = 0; i < 16; ++i) acc[i] = fmaf(f.z, w2[i], acc[i]);
      #pragma unroll
      for (int i = 0; i < 16; ++i) acc[i] = fmaf(f.w, w3[i], acc[i]);
    }
    __syncthreads();  // b3: ALL h1 reads complete before overwrite
    float* hrow = sH + r * SH_PITCH + j0;
    #pragma unroll
    for (int q = 0; q < 4; ++q)
      *(float4*)(hrow + 4 * q) = make_float4(fmaxf(acc[4*q+0], 0.0f), fmaxf(acc[4*q+1], 0.0f),
                                             fmaxf(acc[4*q+2], 0.0f), fmaxf(acc[4*q+3], 0.0f));
  }
  __syncthreads();   // b4: h2 visible

  // ---- phase C: every wave computes mu AND lv for 2 cols (c0 = wv*2). ----
  // Same per-(r,c) fma chains -> bit-identical mu/lv/z. No cross-wave exchange.
  {
    const int c0 = wv * 2;
    const size_t zb = (size_t)(row0 + r) * DZ + c0;
    float2 ev = *(const float2*)(eps + zb);               // issue early, consumed post-loop
    float accM[2], accL[2];
    accM[0] = bmu[c0]; accM[1] = bmu[c0 + 1];
    accL[0] = blv[c0]; accL[1] = blv[c0 + 1];
    const float4* __restrict__ hr = (const float4*)(sH + r * SH_PITCH);
    #pragma unroll 4
    for (int k4 = 0; k4 < HD / 4; ++k4) {
      float4 h4 = hr[k4];
      const float* __restrict__ wm0 = Wmu + (k4 * 4 + 0) * DZ + c0;  // uniform -> s_load
      const float* __restrict__ wm1 = Wmu + (k4 * 4 + 1) * DZ + c0;
      const float* __restrict__ wm2 = Wmu + (k4 * 4 + 2) * DZ + c0;
      const float* __restrict__ wm3 = Wmu + (k4 * 4 + 3) * DZ + c0;
      const float* __restrict__ wl0 = Wlv + (k4 * 4 + 0) * DZ + c0;
      const float* __restrict__ wl1 = Wlv + (k4 * 4 + 1) * DZ + c0;
      const float* __restrict__ wl2 = Wlv + (k4 * 4 + 2) * DZ + c0;
      const float* __restrict__ wl3 = Wlv + (k4 * 4 + 3) * DZ + c0;
      #pragma unroll
      for (int i = 0; i < 2; ++i) {
        accM[i] = fmaf(h4.x, wm0[i], accM[i]);
        accM[i] = fmaf(h4.y, wm1[i], accM[i]);
        accM[i] = fmaf(h4.z, wm2[i], accM[i]);
        accM[i] = fmaf(h4.w, wm3[i], accM[i]);
        accL[i] = fmaf(h4.x, wl0[i], accL[i]);
        accL[i] = fmaf(h4.y, wl1[i], accL[i]);
        accL[i] = fmaf(h4.z, wl2[i], accL[i]);
        accL[i] = fmaf(h4.w, wl3[i], accL[i]);
      }
    }
    float zv0 = fmaf(ev.x, expf(0.5f * accL[0]), accM[0]);
    float zv1 = fmaf(ev.y, expf(0.5f * accL[1]), accM[1]);
    *(float2*)(Zs + r * ZPITCH + c0) = make_float2(zv0, zv1);   // region0, no hazard
    *(float2*)(out + zb)                          = make_float2(zv0, zv1);
    *(float2*)(out + (size_t)NROWS * DZ + zb)     = make_float2(accM[0], accM[1]);
    *(float2*)(out + (size_t)2 * NROWS * DZ + zb) = make_float2(accL[0], accL[1]);
  }
  __syncthreads();   // b5: Zs visible AND all sH reads done -> region1 overlay valid

  // ---- VQ: 8 threads/row, each scans 32 codes (ascending; strict < = argmin) ----
  float zreg[16];
  {
    const float4* __restrict__ zr = (const float4*)(Zs + r * ZPITCH);
    #pragma unroll
    for (int q = 0; q < 4; ++q) {
      float4 z4 = zr[q];
      zreg[4*q+0] = z4.x; zreg[4*q+1] = z4.y; zreg[4*q+2] = z4.z; zreg[4*q+3] = z4.w;
    }
  }
  {
    const int kk0 = wv * 32;
    float bd = 3.0e38f;
    int bi = kk0;
    #pragma unroll 8
    for (int c = 0; c < 32; ++c) {
      int kk = kk0 + c;
      const float* __restrict__ crow = codebook + kk * DZ;  // uniform -> s_load
      float dot = 0.0f;
      #pragma unroll
      for (int i = 0; i < 16; ++i) dot = fmaf(zreg[i], crow[i], dot);
      float s = fmaf(-2.0f, dot, cnormS[kk]);
      if (s < bd) { bd = s; bi = kk; }
    }
    bestdS[wv * 64 + r] = bd;
    bestiS[wv * 64 + r] = bi;
  }
  __syncthreads();   // b6: bestd/besti visible (last barrier)

  // ---- merge (wave 0): argmin across groups, gather z_q, loss partial, stores ----
  if (t < 64) {
    float bd = bestdS[r];
    int   bi = bestiS[r];
    #pragma unroll
    for (int g = 1; g < NWAVE; ++g) {   // ascending groups, strict <: lowest idx wins ties
      float d2 = bestdS[g * 64 + r];
      int   i2 = bestiS[g * 64 + r];
      if (d2 < bd) { bd = d2; bi = i2; }
    }
    const float4* __restrict__ cq = (const float4*)(codebook + bi * DZ);
    float4 q0 = cq[0], q1 = cq[1], q2 = cq[2], q3 = cq[3];
    const size_t base = (size_t)(row0 + r) * DZ;
    float4* __restrict__ gq = (float4*)(out + (size_t)3 * NROWS * DZ + base);
    gq[0] = q0; gq[1] = q1; gq[2] = q2; gq[3] = q3;

    float qq[16] = {q0.x,q0.y,q0.z,q0.w, q1.x,q1.y,q1.z,q1.w,
                    q2.x,q2.y,q2.z,q2.w, q3.x,q3.y,q3.z,q3.w};
    float lsum = 0.0f;
    #pragma unroll
    for (int i = 0; i < 16; ++i) {
      float d = qq[i] - zreg[i];        // zreg IS row r's z for wave 0 (bit-exact)
      lsum = fmaf(d, d, lsum);
    }
    #pragma unroll
    for (int off = 32; off > 0; off >>= 1) lsum += __shfl_down(lsum, off);
    if (t == 0) atomicAdd(loss_ws, lsum);
  }
}

__global__ void encoder_zero(float* ws) {
  if (threadIdx.x == 0 && blockIdx.x == 0) ws[0] = 0.0f;
}

__global__ void encoder_finalize(const float* __restrict__ ws, float* __restrict__ out) {
  if (threadIdx.x == 0 && blockIdx.x == 0) {
    // vq_loss = BETA * (commit + code) = 2*BETA*mean((zq-z)^2)
    out[(size_t)4 * NROWS * DZ] = ws[0] * (2.0f * BETA / (float)((size_t)NROWS * DZ));
  }
}

extern "C" void kernel_launch(void* const* d_in, const int* in_sizes, int n_in,
                              void* d_out, int out_size, void* d_ws, size_t ws_size,
                              hipStream_t stream) {
  (void)in_sizes; (void)n_in; (void)out_size; (void)ws_size;
  const float* feats    = (const float*)d_in[0];
  const float* W1       = (const float*)d_in[1];
  const float* b1       = (const float*)d_in[2];
  const float* W2       = (const float*)d_in[3];
  const float* b2       = (const float*)d_in[4];
  const float* Wmu      = (const float*)d_in[5];
  const float* bmu      = (const float*)d_in[6];
  const float* Wlv      = (const float*)d_in[7];
  const float* blv      = (const float*)d_in[8];
  const float* codebook = (const float*)d_in[9];
  const float* eps      = (const float*)d_in[10];
  float* out = (float*)d_out;
  float* ws  = (float*)d_ws;

  hipLaunchKernelGGL(encoder_zero, dim3(1), dim3(64), 0, stream, ws);
  hipLaunchKernelGGL(encoder_main, dim3(NROWS / TILE_R), dim3(NTHR), 0, stream,
                     feats, W1, b1, W2, b2, Wmu, bmu, Wlv, blv, codebook, eps, out, ws);
  hipLaunchKernelGGL(encoder_finalize, dim3(1), dim3(64), 0, stream, ws, out);
}